// Round 9
// baseline (342.984 us; speedup 1.0000x reference)
//
#include <hip/hip_runtime.h>
#include <stdint.h>

#define ALPHA 1.0f

typedef int i32x4 __attribute__((ext_vector_type(4)));

typedef __attribute__((address_space(3))) void lds_void_t;
typedef const __attribute__((address_space(1))) void global_void_t;

__device__ __forceinline__ void async16(const void* g, void* l) {
    __builtin_amdgcn_global_load_lds((global_void_t*)g, (lds_void_t*)l, 16, 0, 0);
}

__device__ __forceinline__ signed char q8(float v, float inv) {
    float f = fminf(fmaxf(v * inv, -127.f), 127.f);
    return (signed char)__float2int_rn(f);
}

// ---------------------------------------------------------------------------
// Kernel 1 (merged): blocks [0,M) quantize X token-rows to int8 with per-row
// scale sx; blocks [M, M+ceil(nnz/256)) boundary-detect sorted `rows` into
// rstart/rend.  Rows absent from `rows` leave rstart[r]==rend[r] (poison).
// ---------------------------------------------------------------------------
__global__ __launch_bounds__(256) void prep_kernel(
    const float* __restrict__ x, const int* __restrict__ rows,
    int* __restrict__ rstart, int* __restrict__ rend,
    signed char* __restrict__ X8, float* __restrict__ sx, int M, int nnz) {
    const int b = blockIdx.x;
    if (b < M) {
        __shared__ float red[4];
        const int t = threadIdx.x;
        const float4* xr = (const float4*)(x + (size_t)b * 4096);
        float4 v[4];
        float mx = 0.f;
#pragma unroll
        for (int i = 0; i < 4; i++) {
            v[i] = xr[t * 4 + i];
            mx = fmaxf(mx, fmaxf(fmaxf(fabsf(v[i].x), fabsf(v[i].y)),
                                 fmaxf(fabsf(v[i].z), fabsf(v[i].w))));
        }
#pragma unroll
        for (int o = 32; o > 0; o >>= 1) mx = fmaxf(mx, __shfl_xor(mx, o));
        if ((t & 63) == 0) red[t >> 6] = mx;
        __syncthreads();
        mx = fmaxf(fmaxf(red[0], red[1]), fmaxf(red[2], red[3]));
        mx = fmaxf(mx, 1e-20f);
        if (t == 0) sx[b] = mx / 127.f;
        const float inv = 127.f / mx;
        union { signed char c[16]; int4 w; } u;
#pragma unroll
        for (int i = 0; i < 4; i++) {
            u.c[i * 4 + 0] = q8(v[i].x, inv);
            u.c[i * 4 + 1] = q8(v[i].y, inv);
            u.c[i * 4 + 2] = q8(v[i].z, inv);
            u.c[i * 4 + 3] = q8(v[i].w, inv);
        }
        ((int4*)(X8 + (size_t)b * 4096))[t] = u.w;
    } else {
        int i = (b - M) * 256 + threadIdx.x;
        if (i < nnz) {
            int r = rows[i];
            if (i == 0 || rows[i - 1] != r) rstart[r] = i;
            if (i == nnz - 1 || rows[i + 1] != r) rend[r] = i + 1;
        }
    }
}

// ---------------------------------------------------------------------------
// Kernel 2 v2: build int8 W, one output row per block.  (unchanged)
//   Dense dequant in registers; LDS only for the sparse scatter (swizzled).
// ---------------------------------------------------------------------------
__global__ __launch_bounds__(256) void build_w8_kernel(
    const int* __restrict__ packed, const float* __restrict__ scales,
    const float* __restrict__ vals, const int* __restrict__ cols,
    const int* __restrict__ rstart, const int* __restrict__ rend,
    signed char* __restrict__ W8, float* __restrict__ sw) {
    __shared__ __align__(16) float acc[4096];   // sparse-only, swizzled
    __shared__ float red[4];
    const int r = blockIdx.x;
    const int t = threadIdx.x;
    const float s = scales[r];

    const int4* prow4 = (const int4*)(packed + (size_t)r * 2048);
    int4 p0 = prow4[2 * t], p1 = prow4[2 * t + 1];

    const int lo = rstart[r], hi = rend[r];   // equal (poison) if row empty

    float4 sp[4] = {float4{0,0,0,0}, float4{0,0,0,0},
                    float4{0,0,0,0}, float4{0,0,0,0}};
    if (hi > lo) {                             // block-uniform branch
        char* ab = (char*)acc;
#pragma unroll
        for (int i = 0; i < 4; i++) {
            int b = 64 * t + 16 * i;
            *(float4*)(ab + (b ^ (((b >> 7) & 7) << 4))) = float4{0, 0, 0, 0};
        }
        __syncthreads();
        for (int i = lo + t; i < hi; i += 256) {
            int b = cols[i] * 4;
            atomicAdd((float*)(ab + (b ^ (((b >> 7) & 7) << 4))),
                      vals[i] * ALPHA);
        }
        __syncthreads();
#pragma unroll
        for (int i = 0; i < 4; i++) {
            int b = 64 * t + 16 * i;
            sp[i] = *(const float4*)(ab + (b ^ (((b >> 7) & 7) << 4)));
        }
    }

    float w[16];
    {
        int pv[8] = {p0.x, p0.y, p0.z, p0.w, p1.x, p1.y, p1.z, p1.w};
#pragma unroll
        for (int q = 0; q < 8; q++) {
            w[2 * q]     = (float)((pv[q] & 0xF) - 8) * s;
            w[2 * q + 1] = (float)(((pv[q] >> 4) & 0xF) - 8) * s;
        }
    }
    const float* spf = (const float*)sp;
    float mx = 0.f;
#pragma unroll
    for (int k = 0; k < 16; k++) {
        w[k] += spf[k];
        mx = fmaxf(mx, fabsf(w[k]));
    }
#pragma unroll
    for (int o = 32; o > 0; o >>= 1) mx = fmaxf(mx, __shfl_xor(mx, o));
    if ((t & 63) == 0) red[t >> 6] = mx;
    __syncthreads();
    mx = fmaxf(fmaxf(red[0], red[1]), fmaxf(red[2], red[3]));
    mx = fmaxf(mx, 1e-20f);
    if (t == 0) sw[r] = mx / 127.f;
    const float inv = 127.f / mx;

    union { signed char c[16]; int4 v; } u;
#pragma unroll
    for (int k = 0; k < 16; k++) u.c[k] = q8(w[k], inv);
    ((int4*)(W8 + (size_t)r * 4096))[t] = u.v;
}

// ---------------------------------------------------------------------------
// Kernel 3: int8 NT GEMM, fat-wave variant of the proven r3/r8 pipeline.
//   BM=128, BN=256, BK=128 bytes; 256 thr = 4 waves (2M x 2N), 64x128/wave.
//   Rationale: LDS read traffic scales with (WM+WN)/(WM*WN); 64x128 waves
//   cut per-iter ds_read_b128 from 128 to 96 per CU (LDS pipe 1911->1530
//   cyc) while MFMA work/SIMD is unchanged (64/wave x 4 waves) and grid
//   stays 688.  Same 48KB buffer, triple-buffered (147KB), distance 2,
//   counted vmcnt(12) (= 12 stages/iter in flight for tile it+2); same
//   swizzle algebra and read-after-(vmcnt+barrier) discipline as r3/r8.
//   __launch_bounds__(256,1): 1 wave/EU -> 512 VGPR cap, no spills
//   (r6 lesson: spills corrupt counted vmcnt).
// ---------------------------------------------------------------------------
__global__ __launch_bounds__(256, 1) void gemm_kernel(
    const signed char* __restrict__ Xq,   // [M,K] i8
    const signed char* __restrict__ Wq,   // [N,K] i8
    const float* __restrict__ sx,         // [M]
    const float* __restrict__ sw,         // [N]
    float* __restrict__ C,                // [M,N] fp32
    int M, int N, int K) {
    __shared__ __align__(16) signed char smem[3 * 49152];

    const int tid  = threadIdx.x;
    const int wid  = tid >> 6;
    const int lane = tid & 63;
    const int wr = wid >> 1;        // 0..1 (M)
    const int wc = wid & 1;         // 0..1 (N)

    // bijective XCD-chunked block swizzle (nwg = 688, %8 == 0)
    const int nwg = gridDim.x;
    const int bid = blockIdx.x;
    const int qc = nwg >> 3, rr = nwg & 7;
    const int xcd = bid & 7, loc = bid >> 3;
    const int swz = (xcd < rr ? xcd * (qc + 1) : rr * (qc + 1) + (xcd - rr) * qc) + loc;
    const int tm = M >> 7;
    const int mt = swz % tm;
    const int nt = swz / tm;
    const int m0 = mt << 7;
    const int n0 = nt << 8;

    // staging: gload_lds dest linear, global SOURCE pre-swizzled (rule 21).
    // 256 thr x 16B = 4KB/round = 32 rows of 128B.
    const int sr = tid >> 3;                         // row within 32-row group
    const int sc = ((tid & 7) ^ (sr & 7)) << 4;      // swizzled src byte col
    const int lw = wid << 10;                        // wave-uniform LDS chunk

    const signed char* Ax = Xq + (size_t)m0 * K;
    const signed char* Bw = Wq + (size_t)n0 * K;

    // A tile: rows 0..127 -> [buf .. +16K); B tile: rows 0..255 -> [+16K .. +48K)
#define STAGE_A(gbase, ldsbase) do {                                         \
        _Pragma("unroll")                                                    \
        for (int i_ = 0; i_ < 4; i_++)                                       \
            async16((gbase) + (size_t)(i_ * 32 + sr) * K + sc,               \
                    (ldsbase) + i_ * 4096 + lw);                             \
    } while (0)
#define STAGE_B(gbase, ldsbase, h) do {                                      \
        _Pragma("unroll")                                                    \
        for (int i_ = 0; i_ < 4; i_++)                                       \
            async16((gbase) + (size_t)((h) * 128 + i_ * 32 + sr) * K + sc,   \
                    (ldsbase) + 16384 + (h) * 16384 + i_ * 4096 + lw);       \
    } while (0)

    // fragment read constants (identical verified swizzle algebra)
    const int fm = lane & 15;
    const int slot0 = ((lane >> 4) ^ (lane & 7)) << 4;   // k-substep 0
    const int slot1 = slot0 ^ 64;                        // k-substep 1
    const int arow_base = wr * 64;
    const int brow_base = wc * 128;

#define LDA(buf, mi, sl) \
    (*(const i32x4*)((buf) + (size_t)(arow_base + (mi) * 16 + fm) * 128 + (sl)))
#define LDB(buf, nj, sl) \
    (*(const i32x4*)((buf) + 16384 + (size_t)(brow_base + (nj) * 16 + fm) * 128 + (sl)))

    // 16 MFMAs: acc[mi][njb+j] += A[mi] x B[j], mi 0..3, j 0..3
#define MFMA16(A0_, A1_, A2_, A3_, B0_, B1_, B2_, B3_, njb) do {            \
        __builtin_amdgcn_s_setprio(1);                                      \
        acc[0][(njb)+0] = __builtin_amdgcn_mfma_i32_16x16x64_i8(A0_, B0_, acc[0][(njb)+0], 0, 0, 0); \
        acc[1][(njb)+0] = __builtin_amdgcn_mfma_i32_16x16x64_i8(A1_, B0_, acc[1][(njb)+0], 0, 0, 0); \
        acc[2][(njb)+0] = __builtin_amdgcn_mfma_i32_16x16x64_i8(A2_, B0_, acc[2][(njb)+0], 0, 0, 0); \
        acc[3][(njb)+0] = __builtin_amdgcn_mfma_i32_16x16x64_i8(A3_, B0_, acc[3][(njb)+0], 0, 0, 0); \
        acc[0][(njb)+1] = __builtin_amdgcn_mfma_i32_16x16x64_i8(A0_, B1_, acc[0][(njb)+1], 0, 0, 0); \
        acc[1][(njb)+1] = __builtin_amdgcn_mfma_i32_16x16x64_i8(A1_, B1_, acc[1][(njb)+1], 0, 0, 0); \
        acc[2][(njb)+1] = __builtin_amdgcn_mfma_i32_16x16x64_i8(A2_, B1_, acc[2][(njb)+1], 0, 0, 0); \
        acc[3][(njb)+1] = __builtin_amdgcn_mfma_i32_16x16x64_i8(A3_, B1_, acc[3][(njb)+1], 0, 0, 0); \
        acc[0][(njb)+2] = __builtin_amdgcn_mfma_i32_16x16x64_i8(A0_, B2_, acc[0][(njb)+2], 0, 0, 0); \
        acc[1][(njb)+2] = __builtin_amdgcn_mfma_i32_16x16x64_i8(A1_, B2_, acc[1][(njb)+2], 0, 0, 0); \
        acc[2][(njb)+2] = __builtin_amdgcn_mfma_i32_16x16x64_i8(A2_, B2_, acc[2][(njb)+2], 0, 0, 0); \
        acc[3][(njb)+2] = __builtin_amdgcn_mfma_i32_16x16x64_i8(A3_, B2_, acc[3][(njb)+2], 0, 0, 0); \
        acc[0][(njb)+3] = __builtin_amdgcn_mfma_i32_16x16x64_i8(A0_, B3_, acc[0][(njb)+3], 0, 0, 0); \
        acc[1][(njb)+3] = __builtin_amdgcn_mfma_i32_16x16x64_i8(A1_, B3_, acc[1][(njb)+3], 0, 0, 0); \
        acc[2][(njb)+3] = __builtin_amdgcn_mfma_i32_16x16x64_i8(A2_, B3_, acc[2][(njb)+3], 0, 0, 0); \
        acc[3][(njb)+3] = __builtin_amdgcn_mfma_i32_16x16x64_i8(A3_, B3_, acc[3][(njb)+3], 0, 0, 0); \
        __builtin_amdgcn_s_setprio(0);                                      \
    } while (0)

    i32x4 acc[4][8];
#pragma unroll
    for (int i = 0; i < 4; i++)
#pragma unroll
        for (int j = 0; j < 8; j++) acc[i][j] = (i32x4){0, 0, 0, 0};

    const int NT = K >> 7;   // 128-byte K-tiles (32)

    // prologue: stage T0 -> buf0 (12), T1 -> buf1 (12); wait T0 (oldest 12
    // of 24), barrier.
    STAGE_A(Ax,       smem);
    STAGE_B(Bw,       smem, 0);
    STAGE_B(Bw,       smem, 1);
    STAGE_A(Ax + 128, smem + 49152);
    STAGE_B(Bw + 128, smem + 49152, 0);
    STAGE_B(Bw + 128, smem + 49152, 1);
    asm volatile("s_waitcnt vmcnt(12)" ::: "memory");
    __builtin_amdgcn_s_barrier();
    __builtin_amdgcn_sched_barrier(0);

    int cur = 0;
    for (int it = 0; it < NT; ++it) {
        signed char* Ab = smem + cur * 49152;
        int pb = cur + 2; if (pb >= 3) pb -= 3;
        signed char* PA = smem + pb * 49152;
        const bool pref = (it + 2 < NT);
        const int kc = (it + 2) << 7;

        // p0 (top-of-iter, after vmcnt+barrier => buf fully landed):
        // read A ks0 + B ks0 lo + B ks0 hi (p1); stage A(it+2); MFMA njb=0 ks0
        i32x4 aA0 = LDA(Ab, 0, slot0), aA1 = LDA(Ab, 1, slot0),
              aA2 = LDA(Ab, 2, slot0), aA3 = LDA(Ab, 3, slot0);
        i32x4 bL0 = LDB(Ab, 0, slot0), bL1 = LDB(Ab, 1, slot0),
              bL2 = LDB(Ab, 2, slot0), bL3 = LDB(Ab, 3, slot0);
        i32x4 bH0 = LDB(Ab, 4, slot0), bH1 = LDB(Ab, 5, slot0),
              bH2 = LDB(Ab, 6, slot0), bH3 = LDB(Ab, 7, slot0);
        if (pref) STAGE_A(Ax + kc, PA);
        MFMA16(aA0, aA1, aA2, aA3, bL0, bL1, bL2, bL3, 0);

        // p1: read A ks1 (p2) + B ks1 lo (p2); stage B(it+2) half 0;
        // MFMA njb=4 ks0
        i32x4 aK0 = LDA(Ab, 0, slot1), aK1 = LDA(Ab, 1, slot1),
              aK2 = LDA(Ab, 2, slot1), aK3 = LDA(Ab, 3, slot1);
        i32x4 cL0 = LDB(Ab, 0, slot1), cL1 = LDB(Ab, 1, slot1),
              cL2 = LDB(Ab, 2, slot1), cL3 = LDB(Ab, 3, slot1);
        if (pref) STAGE_B(Bw + kc, PA, 0);
        MFMA16(aA0, aA1, aA2, aA3, bH0, bH1, bH2, bH3, 4);

        // p2: read B ks1 hi (p3); stage B(it+2) half 1; MFMA njb=0 ks1
        i32x4 cH0 = LDB(Ab, 4, slot1), cH1 = LDB(Ab, 5, slot1),
              cH2 = LDB(Ab, 6, slot1), cH3 = LDB(Ab, 7, slot1);
        if (pref) STAGE_B(Bw + kc, PA, 1);
        MFMA16(aK0, aK1, aK2, aK3, cL0, cL1, cL2, cL3, 0);

        // p3: counted vmcnt (tile it+1's 12 stages landed; this iter's 12
        // for it+2 remain in flight), MFMA njb=4 ks1, single barrier.
        if (it + 2 < NT)       { asm volatile("s_waitcnt vmcnt(12)" ::: "memory"); }
        else if (it + 2 == NT) { asm volatile("s_waitcnt vmcnt(0)"  ::: "memory"); }
        MFMA16(aK0, aK1, aK2, aK3, cH0, cH1, cH2, cH3, 4);

        __builtin_amdgcn_s_barrier();
        __builtin_amdgcn_sched_barrier(0);
        cur += 1; if (cur == 3) cur = 0;
    }
#undef STAGE_A
#undef STAGE_B
#undef LDA
#undef LDB
#undef MFMA16

    // epilogue: C/D layout col = lane&15, row = (lane>>4)*4 + reg
    const int cr = (lane >> 4) << 2;
    const int cc = lane & 15;
#pragma unroll
    for (int mi = 0; mi < 4; ++mi) {
        const int row0 = m0 + wr * 64 + mi * 16 + cr;
        float sxv[4];
#pragma unroll
        for (int r = 0; r < 4; ++r) sxv[r] = sx[row0 + r];
#pragma unroll
        for (int nj = 0; nj < 8; ++nj) {
            const int col = n0 + wc * 128 + nj * 16 + cc;
            const float swc = sw[col];
            float* cp = C + (size_t)row0 * N + col;
#pragma unroll
            for (int r = 0; r < 4; ++r)
                cp[(size_t)r * N] = (float)acc[mi][nj][r] * sxv[r] * swc;
        }
    }
}

extern "C" void kernel_launch(void* const* d_in, const int* in_sizes, int n_in,
                              void* d_out, int out_size, void* d_ws, size_t ws_size,
                              hipStream_t stream) {
    const float* x      = (const float*)d_in[0];
    const float* scales = (const float*)d_in[1];
    const float* vals   = (const float*)d_in[2];
    const int* packed   = (const int*)d_in[3];
    const int* rows     = (const int*)d_in[4];
    const int* cols     = (const int*)d_in[5];
    float* out          = (float*)d_out;

    const int OUT  = in_sizes[1];            // 11008
    const int HALF = in_sizes[3] / OUT;      // 2048
    const int IN   = HALF * 2;               // 4096
    const int M    = in_sizes[0] / IN;       // 2048 tokens
    const int NNZ  = in_sizes[2];            // 2250000

    // workspace: i8 W [OUT,IN] | i8 X [M,IN] | sx[M] | sw[OUT] | rstart | rend
    signed char* W8 = (signed char*)d_ws;
    signed char* X8 = W8 + (size_t)OUT * IN;
    float* sx   = (float*)(X8 + (size_t)M * IN);
    float* sw   = sx + M;
    int* rstart = (int*)(sw + OUT);
    int* rend   = rstart + OUT;

    const int boundsBlocks = (NNZ + 255) / 256;
    prep_kernel<<<M + boundsBlocks, 256, 0, stream>>>(x, rows, rstart, rend,
                                                      X8, sx, M, NNZ);
    build_w8_kernel<<<OUT, 256, 0, stream>>>(packed, scales, vals, cols,
                                             rstart, rend, W8, sw);
    const int nwg = (M / 128) * (OUT / 256);   // 16 * 43 = 688, %8 == 0
    gemm_kernel<<<nwg, 256, 0, stream>>>(X8, W8, sx, sw, out, M, OUT, IN);
}